// Round 3
// baseline (763.050 us; speedup 1.0000x reference)
//
#include <hip/hip_runtime.h>
#include <math.h>

// StatisticalFeatureLoss — R2: wave-autonomous row-sweep, zero LDS.
// Each 64-lane block owns a 128-col strip x 64-row band, 2 cols/lane.
// Horizontal convs via ds_bpermute neighbor exchange; vertical convs via
// register shift-rings. pred+target pipelined together; no barriers.

static constexpr int H = 512, W = 512, PLANES = 48;
static constexpr float EPSF = 1e-8f;
static constexpr int BAND = 64;

__global__ void init_acc_kernel(double* acc) {
    if (threadIdx.x < 4) acc[threadIdx.x] = 0.0;
}

__global__ void final_kernel(const double* __restrict__ acc, float* __restrict__ out) {
    if (threadIdx.x == 0) {
        const double npix = (double)PLANES * H * W;
        double tot = acc[0] + acc[1] + 0.5 * acc[2] + 0.001 * acc[3];
        out[0] = (float)(tot / (npix * 12.0));
    }
}

__device__ __forceinline__ float bperm(int addr, float v) {
    return __int_as_float(__builtin_amdgcn_ds_bpermute(addr, __float_as_int(v)));
}

template <int D>
__device__ __forceinline__ void shift2(float2* r) {
#pragma unroll
    for (int j = D - 1; j > 0; --j) r[j] = r[j - 1];
}

template <int K>
__global__ __launch_bounds__(64)
void stat_kernel(const float* __restrict__ pred, const float* __restrict__ targ,
                 double* __restrict__ acc) {
    constexpr int R  = K / 2;
    constexpr int WN = 2 * R + 2;          // h-window floats (serves 2 outputs)
    constexpr int OW = 128 - 4 * R;        // valid output cols per strip
    constexpr int NSTRIP = (W + OW - 1) / OW;   // 5 for K=3,5,7
    constexpr int NBAND  = H / BAND;
    constexpr int D2 = 3 * R + 1;          // hx2 ring depth

    const int b     = blockIdx.x;
    const int band  = b % NBAND;
    const int tmp   = b / NBAND;
    const int strip = tmp % NSTRIP;
    const int plane = tmp / NSTRIP;
    const int t     = threadIdx.x;
    const int o     = strip * OW;
    const int gc0   = o - 2 * R + 2 * t;   // global col of this lane's .x
    const int rb0   = band * BAND;

    const bool iva  = (unsigned)gc0 < (unsigned)W;        // in-image col masks
    const bool ivb  = (unsigned)(gc0 + 1) < (unsigned)W;
    const bool full = (gc0 >= 0) && (gc0 + 1 < W);
    const int  lc   = 2 * t;
    const bool ova  = (lc >= 2 * R) && (lc < 2 * R + OW) && iva;   // output-valid
    const bool ovb  = (lc + 1 >= 2 * R) && (lc + 1 < 2 * R + OW) && ivb;

    // bpermute byte addresses (wrap harmlessly at wave edges — those lanes
    // never emit valid outputs)
    const int aL1 = (t - 1) << 2, aR1 = (t + 1) << 2;
    const int aL2 = (t - 2) << 2, aR2 = (t + 2) << 2;

    // Gaussian weights (reference numerics), forced to SGPRs (lane-uniform)
    float g[K];
    {
        const float sigma = (float)K / 6.0f;
        const float inv2s2 = 1.0f / (2.0f * sigma * sigma);
        float s = 0.0f;
#pragma unroll
        for (int i = 0; i < K; ++i) {
            float c = (float)(i - K / 2);
            g[i] = expf(-c * c * inv2s2);
            s += g[i];
        }
#pragma unroll
        for (int i = 0; i < K; ++i)
            g[i] = __int_as_float(__builtin_amdgcn_readfirstlane(__float_as_int(g[i] / s)));
    }

    // w[j] = field at col (2t - R + j); out.a = sum g[d] w[d], out.b shifted by 1
    auto win = [&](float2 v, float* w) {
        if constexpr (K == 3) {
            w[0] = bperm(aL1, v.y); w[1] = v.x; w[2] = v.y; w[3] = bperm(aR1, v.x);
        } else if constexpr (K == 5) {
            w[0] = bperm(aL1, v.x); w[1] = bperm(aL1, v.y);
            w[2] = v.x; w[3] = v.y;
            w[4] = bperm(aR1, v.x); w[5] = bperm(aR1, v.y);
        } else {
            w[0] = bperm(aL2, v.y);
            w[1] = bperm(aL1, v.x); w[2] = bperm(aL1, v.y);
            w[3] = v.x; w[4] = v.y;
            w[5] = bperm(aR1, v.x); w[6] = bperm(aR1, v.y);
            w[7] = bperm(aR2, v.x);
        }
    };
    auto hconv = [&](const float* w) {
        float a = 0.f, bb = 0.f;
#pragma unroll
        for (int d = 0; d < K; ++d) { a += g[d] * w[d]; bb += g[d] * w[d + 1]; }
        return make_float2(a, bb);
    };
    auto loadrow = [&](const float* p, int y) {
        float2 v = make_float2(0.f, 0.f);
        if ((unsigned)y < (unsigned)H) {
            const float* row = p + ((long)y << 9);
            if (full) v = *(const float2*)(row + gc0);
            else {
                if (iva) v.x = row[gc0];
                if (ivb) v.y = row[gc0 + 1];
            }
        }
        return v;
    };

    const float* srcp[2] = { pred + (size_t)plane * H * W,
                             targ + (size_t)plane * H * W };

    // Register rings (zero-init: keeps warmup garbage finite)
    float2 hxr[2][K], hx2r[2][D2], mnr[2][R + 1], v3r[2][K], v4r[2][K];
#pragma unroll
    for (int s = 0; s < 2; ++s) {
#pragma unroll
        for (int j = 0; j < K; ++j) {
            hxr[s][j] = make_float2(0.f, 0.f);
            v3r[s][j] = make_float2(0.f, 0.f);
            v4r[s][j] = make_float2(0.f, 0.f);
        }
#pragma unroll
        for (int j = 0; j < D2; ++j) hx2r[s][j] = make_float2(0.f, 0.f);
#pragma unroll
        for (int j = 0; j <= R; ++j) mnr[s][j] = make_float2(0.f, 0.f);
    }

    float sums[4] = {0.f, 0.f, 0.f, 0.f};
    const int y0 = rb0 - 2 * R, y1 = rb0 + BAND - 1 + 2 * R;

    float2 nx[2], nxc[2];
#pragma unroll
    for (int s = 0; s < 2; ++s) {
        nx[s]  = loadrow(srcp[s], y0);
        nxc[s] = loadrow(srcp[s], y0 - R);
    }

    for (int y = y0; y <= y1; ++y) {
        float2 cx[2]  = { nx[0], nx[1] };
        float2 cxc[2] = { nxc[0], nxc[1] };
#pragma unroll
        for (int s = 0; s < 2; ++s) {       // prefetch next rows
            nx[s]  = loadrow(srcp[s], y + 1);
            nxc[s] = loadrow(srcp[s], y + 1 - R);
        }
        const bool rok = (unsigned)(y - R) < (unsigned)H;   // row of u3/u4

#pragma unroll
        for (int s = 0; s < 2; ++s) {
            float w[WN], w2[WN];
            win(cx[s], w);
#pragma unroll
            for (int j = 0; j < WN; ++j) w2[j] = w[j] * w[j];
            float2 hx = hconv(w);
            float2 hq = hconv(w2);
            shift2<K>(hxr[s]);   hxr[s][0]  = hx;
            shift2<D2>(hx2r[s]); hx2r[s][0] = hq;

            // mean at row c1 = y-R
            float2 mn = make_float2(0.f, 0.f);
#pragma unroll
            for (int d = 0; d < K; ++d) {
                mn.x += g[d] * hxr[s][2 * R - d].x;
                mn.y += g[d] * hxr[s][2 * R - d].y;
            }
            shift2<R + 1>(mnr[s]); mnr[s][0] = mn;

            // u3/u4 at c1 (zero outside image — conv zero-pads the xc FIELD)
            float xca = cxc[s].x - mn.x, xcb = cxc[s].y - mn.y;
            float p3a = xca * xca * xca, p4a = (xca * xca) * (xca * xca);
            float p3b = xcb * xcb * xcb, p4b = (xcb * xcb) * (xcb * xcb);
            float2 u3v, u4v;
            u3v.x = (rok && iva) ? p3a : 0.f;
            u4v.x = (rok && iva) ? p4a : 0.f;
            u3v.y = (rok && ivb) ? p3b : 0.f;
            u4v.y = (rok && ivb) ? p4b : 0.f;

            win(u3v, w);  float2 v3n = hconv(w);
            win(u4v, w);  float2 v4n = hconv(w);
            shift2<K>(v3r[s]); v3r[s][0] = v3n;
            shift2<K>(v4r[s]); v4r[s][0] = v4n;
        }

        if (y - 2 * R >= rb0) {             // emit features for row c2 = y-2R
            float2 ft[2][4];
#pragma unroll
            for (int s = 0; s < 2; ++s) {
                float2 mean = mnr[s][R];
                float2 msq = make_float2(0.f, 0.f);
                float2 m3  = make_float2(0.f, 0.f);
                float2 m4  = make_float2(0.f, 0.f);
#pragma unroll
                for (int d = 0; d < K; ++d) {
                    msq.x += g[d] * hx2r[s][3 * R - d].x;
                    msq.y += g[d] * hx2r[s][3 * R - d].y;
                    m3.x  += g[d] * v3r[s][2 * R - d].x;
                    m3.y  += g[d] * v3r[s][2 * R - d].y;
                    m4.x  += g[d] * v4r[s][2 * R - d].x;
                    m4.y  += g[d] * v4r[s][2 * R - d].y;
                }
                float vx = fmaxf(msq.x - mean.x * mean.x, EPSF);
                float vy = fmaxf(msq.y - mean.y * mean.y, EPSF);
                float sdx = sqrtf(vx), sdy = sqrtf(vy);
                ft[s][0] = mean;
                ft[s][1] = make_float2(vx, vy);
                ft[s][2] = make_float2(__fdividef(m3.x, sdx * vx + EPSF),
                                       __fdividef(m3.y, sdy * vy + EPSF));
                ft[s][3] = make_float2(__fdividef(m4.x, vx * vx + EPSF),
                                       __fdividef(m4.y, vy * vy + EPSF));
            }
            const float ea = ova ? 1.f : 0.f, eb = ovb ? 1.f : 0.f;
#pragma unroll
            for (int f = 0; f < 4; ++f)
                sums[f] += ea * fabsf(ft[0][f].x - ft[1][f].x)
                         + eb * fabsf(ft[0][f].y - ft[1][f].y);
        }
    }

    // wave reduction (block = 1 wave), 4 atomics/block
#pragma unroll
    for (int f = 0; f < 4; ++f) {
        float v = sums[f];
#pragma unroll
        for (int off = 32; off > 0; off >>= 1) v += __shfl_down(v, off, 64);
        if (t == 0) atomicAdd(&acc[f], (double)v);
    }
}

extern "C" void kernel_launch(void* const* d_in, const int* in_sizes, int n_in,
                              void* d_out, int out_size, void* d_ws, size_t ws_size,
                              hipStream_t stream) {
    const float* pred = (const float*)d_in[0];
    const float* targ = (const float*)d_in[1];
    double* acc = (double*)d_ws;
    float* out = (float*)d_out;

    init_acc_kernel<<<1, 64, 0, stream>>>(acc);

    // NSTRIP = 5 for K=3,5,7; grid = 48 planes * 5 strips * 8 bands = 1920
    stat_kernel<3><<<dim3(PLANES * 5 * (H / BAND)), 64, 0, stream>>>(pred, targ, acc);
    stat_kernel<5><<<dim3(PLANES * 5 * (H / BAND)), 64, 0, stream>>>(pred, targ, acc);
    stat_kernel<7><<<dim3(PLANES * 5 * (H / BAND)), 64, 0, stream>>>(pred, targ, acc);

    final_kernel<<<1, 64, 0, stream>>>(acc, out);
}